// Round 7
// baseline (12.830 us; speedup 1.0000x reference)
//
#include <hip/hip_runtime.h>
#include <hip/hip_bf16.h>

// Degree-2 Taylor causal linear attention == causal quadratic attention:
//   Y_S[h,s,:] = (1/64) * sum_{s'<=s} (Q[s]·K[s'])^2 * V[s']
//   Y_Z[h,s]   = (1/64) * sum_{s'<=s} (Q[s]·K[s'])^2
// H=8, S=512, DK=32, DV=64, fp32 in/out.
//
// v7: block = (head, 32-query tile) with 1024 threads = 16 waves (4/SIMD on
// the critical CU, 2x the latency hiding of v6). Wave w = (chunk c=w>>1,
// half e=w&1) owns 32 keys. Plain bf16 QK^T (1 MFMA/tile; error budget ok:
// S,V bf16 already dominate absmax). Zero-VALU bf16 packing via bit-cast.
// Two-stage cross-wave reduce (2 barriers).

typedef __attribute__((ext_vector_type(8))) short short8;   // 8 bf16
typedef __attribute__((ext_vector_type(4))) float floatx4;  // MFMA C/D

constexpr int H_ = 8, S_ = 512, DK = 32, DV = 64;
constexpr float ALPHA = 1.0f / 64.0f;

__device__ __forceinline__ unsigned int pk_bf16(float a, float b) {
    __hip_bfloat162 h = __float22bfloat162_rn(make_float2(a, b));
    union { __hip_bfloat162 h2; unsigned int u; } cvt; cvt.h2 = h;
    return cvt.u;
}
// 8 f32 -> short8 of bf16, no unpack VALU (bit-cast of packed words)
__device__ __forceinline__ short8 pack8(float4 a, float4 b) {
    union { unsigned int u[4]; short8 s; } r;
    r.u[0] = pk_bf16(a.x, a.y); r.u[1] = pk_bf16(a.z, a.w);
    r.u[2] = pk_bf16(b.x, b.y); r.u[3] = pk_bf16(b.z, b.w);
    return r.s;
}

__global__ __launch_bounds__(1024) void taylor_v7(
    const float* __restrict__ Qg, const float* __restrict__ Kg,
    const float* __restrict__ Vg, float* __restrict__ out)
{
    const int t = threadIdx.x;
    const int w = t >> 6;                 // wave 0..15
    const int l = t & 63;
    const int c = w >> 1, e = w & 1;      // chunk, half: keys kb..kb+31
    const int h = blockIdx.x & 7;         // head (spreads XCDs)
    const int qt = 15 - (blockIdx.x >> 3);
    const int qbase = qt * 32;
    const int g = l >> 4, r15 = l & 15;

    const bool active = (w <= qt);        // wave's keys start <= qmax
    const bool last   = (w == qt);        // boundary wave: needs causal mask

    __shared__ alignas(16) char Ssm[16 * 2048];   // per-wave S^T tile, swizzled
    __shared__ alignas(16) float4 Racc[8][8][64]; // [chunk][frag][lane]
    __shared__ float Zb[16][32];                  // per-wave Y_Z partials

    floatx4 acc[2][4] = {};               // [qtile][dtile]
    float zacc[2] = {0.f, 0.f};

    if (active) {
        const int kb = c * 64 + e * 32;   // first key of this wave

        // ---- issue all loads: Q, K first, then V (vmcnt ordering lets
        //      Q/K converts start while V is still in flight) ----
        float4 qraw[2][2];
        #pragma unroll
        for (int qtile = 0; qtile < 2; ++qtile) {
            const float* qp = Qg + (size_t)(h * S_ + qbase + qtile * 16 + r15) * DK + g * 8;
            qraw[qtile][0] = *(const float4*)qp;
            qraw[qtile][1] = *(const float4*)(qp + 4);
        }
        float4 kraw[2][2];
        #pragma unroll
        for (int ktile = 0; ktile < 2; ++ktile) {
            const float* kp = Kg + (size_t)(h * S_ + kb + ktile * 16 + r15) * DK + g * 8;
            kraw[ktile][0] = *(const float4*)kp;
            kraw[ktile][1] = *(const float4*)(kp + 4);
        }
        float vraw[4][8];                 // [dtile][j]: V[kb+g*8+j][dtile*16+r15]
        #pragma unroll
        for (int dtile = 0; dtile < 4; ++dtile) {
            const float* vp = Vg + (size_t)(h * S_ + kb + g * 8) * DV + dtile * 16 + r15;
            #pragma unroll
            for (int j = 0; j < 8; ++j)
                vraw[dtile][j] = vp[(size_t)j * DV];
        }

        // ---- convert Q, K (plain bf16) ----
        short8 qB[2], kA[2];
        #pragma unroll
        for (int i = 0; i < 2; ++i) {
            qB[i] = pack8(qraw[i][0], qraw[i][1]);
            kA[i] = pack8(kraw[i][0], kraw[i][1]);
        }

        char* ssmW = Ssm + w * 2048;

        // ---- QK^T: S^T[k][q]; 2 ktiles x 2 qtiles, 1 MFMA each ----
        #pragma unroll
        for (int ktile = 0; ktile < 2; ++ktile) {
            #pragma unroll
            for (int qtile = 0; qtile < 2; ++qtile) {
                floatx4 cc_ = {0.f, 0.f, 0.f, 0.f};
                cc_ = __builtin_amdgcn_mfma_f32_16x16x32_bf16(kA[ktile], qB[qtile], cc_, 0, 0, 0);
                // C layout: q = col = r15 (+16*qtile), k = row = g*4+rr (+16*ktile)
                const int qg = qbase + qtile * 16 + r15;
                const int k0 = kb + ktile * 16 + g * 4;
                float s[4];
                #pragma unroll
                for (int rr = 0; rr < 4; ++rr) {
                    float sv = cc_[rr] * cc_[rr] * ALPHA;
                    if (last && (k0 + rr > qg)) sv = 0.f;
                    s[rr] = sv;
                }
                zacc[qtile] += (s[0] + s[1]) + (s[2] + s[3]);
                unsigned int p0 = pk_bf16(s[0], s[1]);
                unsigned int p1 = pk_bf16(s[2], s[3]);
                const int qrow = qtile * 16 + r15;
                const int swz = (qrow ^ (qrow >> 2)) & 3;
                const int gi = ktile * 2 + (g >> 1);       // 16B granule (8 keys)
                const int byte = qrow * 64 + ((gi ^ swz) << 4) + (g & 1) * 8;
                *(uint2*)(ssmW + byte) = make_uint2(p0, p1);
            }
        }

        // ---- convert V ----
        short8 vB[4];
        #pragma unroll
        for (int dtile = 0; dtile < 4; ++dtile) {
            union { unsigned int u[4]; short8 s; } r;
            #pragma unroll
            for (int p = 0; p < 4; ++p)
                r.u[p] = pk_bf16(vraw[dtile][2 * p], vraw[dtile][2 * p + 1]);
            vB[dtile] = r.s;
        }

        // ---- PV: Y[q][d] += S[q][32k] * V[32k][d] ----
        short8 sA[2];
        #pragma unroll
        for (int qtile = 0; qtile < 2; ++qtile) {
            const int qrow = qtile * 16 + r15;
            const int swz = (qrow ^ (qrow >> 2)) & 3;
            sA[qtile] = *(const short8*)(ssmW + qrow * 64 + ((g ^ swz) << 4));
        }
        #pragma unroll
        for (int qtile = 0; qtile < 2; ++qtile)
            #pragma unroll
            for (int dtile = 0; dtile < 4; ++dtile)
                acc[qtile][dtile] = __builtin_amdgcn_mfma_f32_16x16x32_bf16(
                    sA[qtile], vB[dtile], acc[qtile][dtile], 0, 0, 0);

        // zacc: sum over the 4 lane-groups -> every lane holds full value
        #pragma unroll
        for (int qtile = 0; qtile < 2; ++qtile) {
            float z = zacc[qtile];
            z += __shfl_xor(z, 16);
            z += __shfl_xor(z, 32);
            zacc[qtile] = z;
        }
    }

    // ---- stage A: half e=1 publishes; everyone publishes Zb ----
    if (e == 1) {
        #pragma unroll
        for (int f = 0; f < 8; ++f) {
            floatx4 a = acc[f >> 2][f & 3];
            Racc[c][f][l] = make_float4(a[0], a[1], a[2], a[3]);
        }
    }
    if (l < 32) Zb[w][l] = (l < 16) ? zacc[0] : zacc[1];
    __syncthreads();

    // ---- stage B: half e=0 folds partner in and publishes chunk total ----
    if (e == 0) {
        #pragma unroll
        for (int f = 0; f < 8; ++f) {
            float4 p = Racc[c][f][l];
            floatx4 a = acc[f >> 2][f & 3];
            Racc[c][f][l] = make_float4(a[0] + p.x, a[1] + p.y, a[2] + p.z, a[3] + p.w);
        }
    }
    __syncthreads();

    // ---- stage C: waves 0..7 tree-sum fragment f=w across 8 chunks ----
    if (w < 8) {
        float4 sum = make_float4(0.f, 0.f, 0.f, 0.f);
        #pragma unroll
        for (int cw = 0; cw < 8; ++cw) {
            float4 v = Racc[cw][w][l];
            sum.x += v.x; sum.y += v.y; sum.z += v.z; sum.w += v.w;
        }
        const int qtile = w >> 2, dtile = w & 3;
        const int d = dtile * 16 + r15;
        float sv[4] = {sum.x, sum.y, sum.z, sum.w};
        #pragma unroll
        for (int rr = 0; rr < 4; ++rr) {
            int q = qbase + qtile * 16 + g * 4 + rr;
            out[(size_t)(h * S_ + q) * DV + d] = sv[rr];
        }
    }
    // ---- Y_Z ----
    if (t < 32) {
        float z = 0.f;
        #pragma unroll
        for (int ww = 0; ww < 16; ++ww) z += Zb[ww][t];
        out[(size_t)(H_ * S_ * DV) + h * S_ + qbase + t] = z;
    }
}

extern "C" void kernel_launch(void* const* d_in, const int* in_sizes, int n_in,
                              void* d_out, int out_size, void* d_ws, size_t ws_size,
                              hipStream_t stream) {
    const float* Q = (const float*)d_in[0];
    const float* K = (const float*)d_in[1];
    const float* V = (const float*)d_in[2];
    // d_in[3]=M, d_in[4]=C folded into the (q.k)^2 identity; d_in[5]=continue_prev==0.
    float* out = (float*)d_out;

    taylor_v7<<<128, 1024, 0, stream>>>(Q, K, V, out);   // single dispatch
}

// Round 8
// 10.204 us; speedup vs baseline: 1.2574x; 1.2574x over previous
//
#include <hip/hip_runtime.h>
#include <hip/hip_bf16.h>

// Degree-2 Taylor causal linear attention == causal quadratic attention:
//   Y_S[h,s,:] = (1/64) * sum_{s'<=s} (Q[s]·K[s'])^2 * V[s']
//   Y_Z[h,s]   = (1/64) * sum_{s'<=s} (Q[s]·K[s'])^2
// H=8, S=512, DK=32, DV=64, fp32 in/out.
//
// v8: 256 blocks x 512 threads (ALL 256 CUs; v6 used only 128).
// Block = (head, 16-query tile); wave c of 8 owns 64-key chunk c.
// Plain bf16 QK^T (1 MFMA/tile; S,V-bf16 error dominates anyway),
// zero-VALU bf16 packing, v6's swizzled S-LDS + transposed Racc.

typedef __attribute__((ext_vector_type(8))) short short8;   // 8 bf16
typedef __attribute__((ext_vector_type(4))) float floatx4;  // MFMA C/D

constexpr int H_ = 8, S_ = 512, DK = 32, DV = 64;
constexpr float ALPHA = 1.0f / 64.0f;

__device__ __forceinline__ unsigned int pk_bf16(float a, float b) {
    __hip_bfloat162 h = __float22bfloat162_rn(make_float2(a, b));
    union { __hip_bfloat162 h2; unsigned int u; } cvt; cvt.h2 = h;
    return cvt.u;
}
// 8 f32 -> short8 bf16, no unpack VALU (bit-cast of packed words)
__device__ __forceinline__ short8 pack8(float4 a, float4 b) {
    union { unsigned int u[4]; short8 s; } r;
    r.u[0] = pk_bf16(a.x, a.y); r.u[1] = pk_bf16(a.z, a.w);
    r.u[2] = pk_bf16(b.x, b.y); r.u[3] = pk_bf16(b.z, b.w);
    return r.s;
}

__global__ __launch_bounds__(512) void taylor_v8(
    const float* __restrict__ Qg, const float* __restrict__ Kg,
    const float* __restrict__ Vg, float* __restrict__ out)
{
    const int t = threadIdx.x;
    const int c = t >> 6;                  // wave id == 64-key chunk id 0..7
    const int l = t & 63;
    const int h = blockIdx.x & 7;          // head (spreads XCDs)
    const int qt = 31 - (blockIdx.x >> 3); // 16-query tile, deep first
    const int qbase = qt * 16;
    const int nc = (qt >> 2) + 1;          // causal chunk count 1..8
    const int g = l >> 4, r15 = l & 15;

    __shared__ alignas(16) char Ssm[8 * 2048];    // per-wave S^T[16q][64k] bf16, swizzled
    __shared__ alignas(16) float4 Racc[8][4][64]; // [chunk][frag][lane]
    __shared__ float Zb[8][16];                   // per-wave Y_Z partials

    floatx4 acc[4] = {};                   // [dtile]
    float zacc = 0.f;

    if (c < nc) {
        const bool lastc = (c == nc - 1);
        const int kb = c * 64;

        // ---- issue all raw loads up-front (Q, K, then V) ----
        float4 qraw[2];
        {
            const float* qp = Qg + (size_t)(h * S_ + qbase + r15) * DK + g * 8;
            qraw[0] = *(const float4*)qp;
            qraw[1] = *(const float4*)(qp + 4);
        }
        float4 kraw[4][2];
        #pragma unroll
        for (int ktile = 0; ktile < 4; ++ktile) {
            const float* kp = Kg + (size_t)(h * S_ + kb + ktile * 16 + r15) * DK + g * 8;
            kraw[ktile][0] = *(const float4*)kp;
            kraw[ktile][1] = *(const float4*)(kp + 4);
        }
        float vraw[2][4][8];               // [kc][dtile][j]: V[kb+kc*32+g*8+j][dtile*16+r15]
        #pragma unroll
        for (int kc = 0; kc < 2; ++kc)
            #pragma unroll
            for (int dtile = 0; dtile < 4; ++dtile) {
                const float* vp = Vg + (size_t)(h * S_ + kb + kc * 32 + g * 8) * DV
                                     + dtile * 16 + r15;
                #pragma unroll
                for (int j = 0; j < 8; ++j)
                    vraw[kc][dtile][j] = vp[(size_t)j * DV];
            }

        // ---- convert Q ----
        short8 qB = pack8(qraw[0], qraw[1]);

        char* ssmW = Ssm + c * 2048;

        // ---- QK^T: S^T[k][q], 4 ktiles, 1 MFMA each ----
        #pragma unroll
        for (int ktile = 0; ktile < 4; ++ktile) {
            short8 kA = pack8(kraw[ktile][0], kraw[ktile][1]);
            floatx4 cc_ = {0.f, 0.f, 0.f, 0.f};
            cc_ = __builtin_amdgcn_mfma_f32_16x16x32_bf16(kA, qB, cc_, 0, 0, 0);
            // C layout: q = col = r15, k = row = g*4 + rr (+16*ktile)
            const int qg = qbase + r15;
            const int k0 = kb + ktile * 16 + g * 4;
            float s[4];
            #pragma unroll
            for (int rr = 0; rr < 4; ++rr) {
                float sv = cc_[rr] * cc_[rr] * ALPHA;
                if (lastc && (k0 + rr > qg)) sv = 0.f;
                s[rr] = sv;
            }
            zacc += (s[0] + s[1]) + (s[2] + s[3]);
            unsigned int p0 = pk_bf16(s[0], s[1]);
            unsigned int p1 = pk_bf16(s[2], s[3]);
            const int kl = ktile * 16 + g * 4;       // key local 0..63
            const int byte = r15 * 128 + (((kl >> 3) ^ (r15 & 7)) << 4) + ((kl & 7) * 2);
            *(uint2*)(ssmW + byte) = make_uint2(p0, p1);
        }

        // ---- convert V ----
        short8 vB[2][4];
        #pragma unroll
        for (int kc = 0; kc < 2; ++kc)
            #pragma unroll
            for (int dtile = 0; dtile < 4; ++dtile) {
                union { unsigned int u[4]; short8 s; } r;
                #pragma unroll
                for (int p = 0; p < 4; ++p)
                    r.u[p] = pk_bf16(vraw[kc][dtile][2 * p], vraw[kc][dtile][2 * p + 1]);
                vB[kc][dtile] = r.s;
            }

        // ---- PV: Y[q][d] += S[q][64k] * V[64k][d] ----
        #pragma unroll
        for (int kc = 0; kc < 2; ++kc) {
            const int gi = kc * 4 + g;               // 8-key granule for A-frag
            short8 sA = *(const short8*)(ssmW + r15 * 128 + ((gi ^ (r15 & 7)) << 4));
            #pragma unroll
            for (int dtile = 0; dtile < 4; ++dtile)
                acc[dtile] = __builtin_amdgcn_mfma_f32_16x16x32_bf16(
                    sA, vB[kc][dtile], acc[dtile], 0, 0, 0);
        }

        // zacc: sum over the 4 lane-groups -> lanes with same r15 share value
        zacc += __shfl_xor(zacc, 16);
        zacc += __shfl_xor(zacc, 32);
    }

    // ---- publish partials (idle waves publish zeros) ----
    #pragma unroll
    for (int f = 0; f < 4; ++f) {
        floatx4 a = acc[f];
        Racc[c][f][l] = make_float4(a[0], a[1], a[2], a[3]);
    }
    if (l < 16) Zb[c][l] = zacc;
    __syncthreads();

    // ---- cross-wave reduce: waves 0..3 own fragment f=w ----
    if (c < 4) {
        float4 sum = make_float4(0.f, 0.f, 0.f, 0.f);
        #pragma unroll
        for (int cw = 0; cw < 8; ++cw) {
            float4 v = Racc[cw][c][l];
            sum.x += v.x; sum.y += v.y; sum.z += v.z; sum.w += v.w;
        }
        const int d = c * 16 + r15;
        float sv[4] = {sum.x, sum.y, sum.z, sum.w};
        #pragma unroll
        for (int rr = 0; rr < 4; ++rr) {
            int q = qbase + g * 4 + rr;
            out[(size_t)(h * S_ + q) * DV + d] = sv[rr];
        }
    }
    // ---- Y_Z ----
    if (t < 16) {
        float z = 0.f;
        #pragma unroll
        for (int cw = 0; cw < 8; ++cw) z += Zb[cw][t];
        out[(size_t)(H_ * S_ * DV) + h * S_ + qbase + t] = z;
    }
}

extern "C" void kernel_launch(void* const* d_in, const int* in_sizes, int n_in,
                              void* d_out, int out_size, void* d_ws, size_t ws_size,
                              hipStream_t stream) {
    const float* Q = (const float*)d_in[0];
    const float* K = (const float*)d_in[1];
    const float* V = (const float*)d_in[2];
    // d_in[3]=M, d_in[4]=C folded into the (q.k)^2 identity; d_in[5]=continue_prev==0.
    float* out = (float*)d_out;

    taylor_v8<<<256, 512, 0, stream>>>(Q, K, V, out);   // single dispatch, 1 block/CU
}